// Round 3
// baseline (257.694 us; speedup 1.0000x reference)
//
#include <hip/hip_runtime.h>
#include <hip/hip_bf16.h>

typedef __attribute__((ext_vector_type(8))) short short8;
typedef __attribute__((ext_vector_type(4))) float float4v;
typedef __attribute__((ext_vector_type(4))) unsigned int uint4v;
typedef __attribute__((ext_vector_type(2))) unsigned int uint2v;

#define SS 8192
#define EE 512
#define NKB 16
#define AP 520    // A row pitch in shorts (1040 B = 65*16B, odd -> bank-uniform b128 reads)

__device__ __forceinline__ unsigned int f2bf1(float f) {
    unsigned int u = __builtin_bit_cast(unsigned int, f);
    return (u + 0x7fffu + ((u >> 16) & 1u)) >> 16;   // RNE, inputs finite
}
__device__ __forceinline__ unsigned int pack2(float lo, float hi) {
    return f2bf1(lo) | (f2bf1(hi) << 16);
}

// ---------- prep: W fp32 [512][512] -> bf16 ws [kb][n][32] (linear, no swizzle) ----------
__global__ void w_prep(const float* __restrict__ W, unsigned short* __restrict__ Wws) {
    int idx = blockIdx.x * 256 + threadIdx.x;        // 65536 threads x 4 elems
    int n  = idx >> 7;                               // W row (= output col) 0..511
    int kg = idx & 127;
    int k  = kg * 4;
    float4v v = *(const float4v*)(W + (size_t)n * EE + k);
    int kb = k >> 5, kl = k & 31;
    unsigned short* dst = Wws + ((size_t)kb * (EE * 32) + (size_t)n * 32 + kl);
    uint2v pk = { pack2(v.x, v.y), pack2(v.z, v.w) };
    *(uint2v*)dst = pk;
}

// ---------- main v5: A staged whole in LDS, W streamed global->VGPR, ZERO k-loop barriers ----------
// Block = (b, sc): 64x512 output panel. A[64][512] bf16 staged once (cos fused),
// then 16 K-iterations of {prefetch next 8 b-frags from L2, 4 a ds_reads, 32 MFMA}.
// Waves are fully decoupled after the single post-staging __syncthreads().
__global__ __launch_bounds__(256, 2)
void qmha_fused5(const float* __restrict__ x, const float* __restrict__ theta,
                 const unsigned short* __restrict__ Wws, float* __restrict__ out)
{
    __shared__ __attribute__((aligned(16))) unsigned short A_lds[64 * AP];  // 66560 B

    const int bx = blockIdx.x;                       // 1024 blocks
    const int b  = bx >> 7;
    const int sc = bx & 127;
    const int t = threadIdx.x, lane = t & 63, wid = t >> 6;
    const int fr = lane & 15, q = lane >> 4;

    // b-frag global base: wave wid owns W rows [wid*128, +128). Frag nt of slice kb:
    // Wws + kb*16384 + (wid*128 + nt*16 + fr)*32 + q*8  (1 KB contiguous per frag -> coalesced)
    const unsigned short* wbase = Wws + ((size_t)(wid * 128 + fr) * 32 + q * 8);

    // Prefetch b-frags for kb=0 before staging (lands under the staging phase).
    short8 bA[8], bB[8];
    #pragma unroll
    for (int nt = 0; nt < 8; ++nt)
        bA[nt] = *(const short8*)(wbase + nt * 512);

    const float th0 = theta[0], th1 = theta[1], th2 = theta[2], th3 = theta[3];
    const float th4 = theta[4], th5 = theta[5], th6 = theta[6], th7 = theta[7];

    // ---- A staging: A[m][e] = cos(x[b, sc*64 + e/8, m*8 + e%8] + theta[e%8]) ----
    // Wave wid covers x rows sc*64 + wid*16 .. +16; lane covers x cols lane*8..+8 (m = lane).
    {
        const float* xb = x + ((size_t)b * SS + (size_t)sc * 64 + (size_t)wid * 16) * EE + lane * 8;
        unsigned short* aw = A_lds + lane * AP + wid * 128;   // col base = (wid*16+it)*8
        #pragma unroll
        for (int it = 0; it < 16; ++it) {
            const float* px = xb + (size_t)it * EE;
            float4v v0 = *(const float4v*)(px);
            float4v v1 = *(const float4v*)(px + 4);
            float c0 = __cosf(v0.x + th0), c1 = __cosf(v0.y + th1);
            float c2 = __cosf(v0.z + th2), c3 = __cosf(v0.w + th3);
            float c4 = __cosf(v1.x + th4), c5 = __cosf(v1.y + th5);
            float c6 = __cosf(v1.z + th6), c7 = __cosf(v1.w + th7);
            uint4v pk = { pack2(c0,c1), pack2(c2,c3), pack2(c4,c5), pack2(c6,c7) };
            *(uint4v*)(aw + it * 8) = pk;
        }
    }

    __syncthreads();   // the ONLY block-wide sync: A visible to all waves

    float4v acc[4][8];
    #pragma unroll
    for (int i = 0; i < 4; ++i)
        #pragma unroll
        for (int j = 0; j < 8; ++j)
            acc[i][j] = (float4v){0.f, 0.f, 0.f, 0.f};

    const int aoff = fr * AP + q * 8;                // + mt*16*AP + kb*32

    // ---- K-loop: no barriers, counted waits compiler-managed, 2x unroll (static bufs) ----
    #pragma unroll
    for (int kb = 0; kb < NKB; kb += 2) {
        // prefetch b for kb+1 into bB (always valid: kb+1 <= 15)
        {
            const unsigned short* wn = wbase + (size_t)(kb + 1) * (EE * 32);
            #pragma unroll
            for (int nt = 0; nt < 8; ++nt)
                bB[nt] = *(const short8*)(wn + nt * 512);
        }
        {
            short8 af[4];
            #pragma unroll
            for (int mt = 0; mt < 4; ++mt)
                af[mt] = *(const short8*)&A_lds[aoff + mt * 16 * AP + kb * 32];
            __builtin_amdgcn_s_setprio(1);
            #pragma unroll
            for (int nt = 0; nt < 8; ++nt)
                #pragma unroll
                for (int mt = 0; mt < 4; ++mt)
                    acc[mt][nt] = __builtin_amdgcn_mfma_f32_16x16x32_bf16(af[mt], bA[nt], acc[mt][nt], 0, 0, 0);
            __builtin_amdgcn_s_setprio(0);
        }
        // prefetch b for kb+2 into bA
        if (kb + 2 < NKB) {
            const unsigned short* wn = wbase + (size_t)(kb + 2) * (EE * 32);
            #pragma unroll
            for (int nt = 0; nt < 8; ++nt)
                bA[nt] = *(const short8*)(wn + nt * 512);
        }
        {
            short8 af[4];
            #pragma unroll
            for (int mt = 0; mt < 4; ++mt)
                af[mt] = *(const short8*)&A_lds[aoff + mt * 16 * AP + (kb + 1) * 32];
            __builtin_amdgcn_s_setprio(1);
            #pragma unroll
            for (int nt = 0; nt < 8; ++nt)
                #pragma unroll
                for (int mt = 0; mt < 4; ++mt)
                    acc[mt][nt] = __builtin_amdgcn_mfma_f32_16x16x32_bf16(af[mt], bB[nt], acc[mt][nt], 0, 0, 0);
            __builtin_amdgcn_s_setprio(0);
        }
    }

    // ---- epilogue: C/D col=lane&15, row=(lane>>4)*4+reg (validated mapping) ----
    // out(m = mt*16 + q*4 + r, n = wid*128 + nt*16 + fr) at [b, m*128+sc, n]
    float* outb = out + (size_t)b * (SS * EE) + (size_t)sc * EE + wid * 128 + fr;
    #pragma unroll
    for (int mt = 0; mt < 4; ++mt) {
        #pragma unroll
        for (int r = 0; r < 4; ++r) {
            const int m = mt * 16 + q * 4 + r;
            float* po = outb + (size_t)m * (128 * EE);
            #pragma unroll
            for (int nt = 0; nt < 8; ++nt)
                po[nt * 16] = acc[mt][nt][r];
        }
    }
}

// ---------- fallback (round-1 kernel, used only if ws too small) ----------
#define AS 520
#define WSF 40
#define HH 64
__global__ __launch_bounds__(256, 2)
void qmha_fused_fb(const float* __restrict__ x, const float* __restrict__ theta,
                   const float* __restrict__ W, float* __restrict__ out)
{
    __shared__ __attribute__((aligned(16))) unsigned short A_lds[HH * AS];
    __shared__ __attribute__((aligned(16))) unsigned short W_lds[128 * WSF];
    const int bx = blockIdx.x;
    const int ntile = (bx >> 3) & 3;
    const int p = ((bx >> 5) << 3) | (bx & 7);
    const int b = p >> 7;
    const int sc = p & 127;
    const int t = threadIdx.x, lane = t & 63, wid = t >> 6;
    const int wn = t >> 1, wk = (t & 1) * 16;
    const float* Wbase = W + (size_t)(ntile * 128 + wn) * EE + wk;
    float4v wv0 = *(const float4v*)(Wbase + 0);
    float4v wv1 = *(const float4v*)(Wbase + 4);
    float4v wv2 = *(const float4v*)(Wbase + 8);
    float4v wv3 = *(const float4v*)(Wbase + 12);
    const float th0 = theta[0], th1 = theta[1], th2 = theta[2], th3 = theta[3];
    const float th4 = theta[4], th5 = theta[5], th6 = theta[6], th7 = theta[7];
    {
        const float* xb = x + ((size_t)b * SS + (size_t)sc * 64) * EE + lane * 8;
        #pragma unroll
        for (int it = 0; it < 16; ++it) {
            const int s_loc = wid * 16 + it;
            const float* px = xb + (size_t)s_loc * EE;
            float4v v0 = *(const float4v*)(px);
            float4v v1 = *(const float4v*)(px + 4);
            float c0 = __cosf(v0.x + th0), c1 = __cosf(v0.y + th1);
            float c2 = __cosf(v0.z + th2), c3 = __cosf(v0.w + th3);
            float c4 = __cosf(v1.x + th4), c5 = __cosf(v1.y + th5);
            float c6 = __cosf(v1.z + th6), c7 = __cosf(v1.w + th7);
            uint4v pk = { pack2(c0,c1), pack2(c2,c3), pack2(c4,c5), pack2(c6,c7) };
            *(uint4v*)&A_lds[lane * AS + s_loc * 8] = pk;
        }
    }
    float4v acc[2][4];
    #pragma unroll
    for (int i = 0; i < 2; ++i)
        #pragma unroll
        for (int j = 0; j < 4; ++j)
            acc[i][j] = (float4v){0.f, 0.f, 0.f, 0.f};
    const int m0 = (wid >> 1) * 32, n0l = (wid & 1) * 64;
    const int fr = lane & 15, q = lane >> 4;
    const unsigned short* Arow0 = &A_lds[(m0 + fr) * AS + q * 8];
    const unsigned short* Arow1 = Arow0 + 16 * AS;
    const unsigned short* Wrow  = &W_lds[(n0l + fr) * WSF + q * 8];
    for (int kb = 0; kb < NKB; ++kb) {
        __syncthreads();
        {
            uint4v lo = { pack2(wv0.x, wv0.y), pack2(wv0.z, wv0.w),
                          pack2(wv1.x, wv1.y), pack2(wv1.z, wv1.w) };
            uint4v hi = { pack2(wv2.x, wv2.y), pack2(wv2.z, wv2.w),
                          pack2(wv3.x, wv3.y), pack2(wv3.z, wv3.w) };
            *(uint4v*)&W_lds[wn * WSF + wk]     = lo;
            *(uint4v*)&W_lds[wn * WSF + wk + 8] = hi;
        }
        if (kb < NKB - 1) {
            const float* Wn = Wbase + (size_t)(kb + 1) * 32;
            wv0 = *(const float4v*)(Wn + 0);
            wv1 = *(const float4v*)(Wn + 4);
            wv2 = *(const float4v*)(Wn + 8);
            wv3 = *(const float4v*)(Wn + 12);
        }
        __syncthreads();
        short8 a0 = *(const short8*)(Arow0 + kb * 32);
        short8 a1 = *(const short8*)(Arow1 + kb * 32);
        short8 b0 = *(const short8*)(Wrow + 0 * 16 * WSF);
        short8 b1 = *(const short8*)(Wrow + 1 * 16 * WSF);
        short8 b2 = *(const short8*)(Wrow + 2 * 16 * WSF);
        short8 b3 = *(const short8*)(Wrow + 3 * 16 * WSF);
        acc[0][0] = __builtin_amdgcn_mfma_f32_16x16x32_bf16(a0, b0, acc[0][0], 0, 0, 0);
        acc[0][1] = __builtin_amdgcn_mfma_f32_16x16x32_bf16(a0, b1, acc[0][1], 0, 0, 0);
        acc[0][2] = __builtin_amdgcn_mfma_f32_16x16x32_bf16(a0, b2, acc[0][2], 0, 0, 0);
        acc[0][3] = __builtin_amdgcn_mfma_f32_16x16x32_bf16(a0, b3, acc[0][3], 0, 0, 0);
        acc[1][0] = __builtin_amdgcn_mfma_f32_16x16x32_bf16(a1, b0, acc[1][0], 0, 0, 0);
        acc[1][1] = __builtin_amdgcn_mfma_f32_16x16x32_bf16(a1, b1, acc[1][1], 0, 0, 0);
        acc[1][2] = __builtin_amdgcn_mfma_f32_16x16x32_bf16(a1, b2, acc[1][2], 0, 0, 0);
        acc[1][3] = __builtin_amdgcn_mfma_f32_16x16x32_bf16(a1, b3, acc[1][3], 0, 0, 0);
    }
    const int colbase = ntile * 128 + n0l + fr;
    #pragma unroll
    for (int mt = 0; mt < 2; ++mt) {
        #pragma unroll
        for (int r = 0; r < 4; ++r) {
            const int hrow = m0 + mt * 16 + q * 4 + r;
            float* po = out + ((size_t)b * SS + (size_t)hrow * 128 + sc) * EE + colbase;
            po[0 * 16] = acc[mt][0][r];
            po[1 * 16] = acc[mt][1][r];
            po[2 * 16] = acc[mt][2][r];
            po[3 * 16] = acc[mt][3][r];
        }
    }
}

extern "C" void kernel_launch(void* const* d_in, const int* in_sizes, int n_in,
                              void* d_out, int out_size, void* d_ws, size_t ws_size,
                              hipStream_t stream) {
    const float* x     = (const float*)d_in[0];
    const float* theta = (const float*)d_in[1];
    const float* W     = (const float*)d_in[2];
    float* out         = (float*)d_out;

    if (ws_size >= (size_t)EE * EE * sizeof(unsigned short)) {
        unsigned short* Wws = (unsigned short*)d_ws;
        w_prep<<<dim3(256), dim3(256), 0, stream>>>(W, Wws);
        qmha_fused5<<<dim3(1024), dim3(256), 0, stream>>>(x, theta, Wws, out);
    } else {
        qmha_fused_fb<<<dim3(4096), dim3(256), 0, stream>>>(x, theta, W, out);
    }
}

// Round 4
// 251.701 us; speedup vs baseline: 1.0238x; 1.0238x over previous
//
#include <hip/hip_runtime.h>
#include <hip/hip_bf16.h>

typedef __attribute__((ext_vector_type(8))) short short8;
typedef __attribute__((ext_vector_type(4))) float float4v;
typedef __attribute__((ext_vector_type(4))) unsigned int uint4v;
typedef __attribute__((ext_vector_type(2))) unsigned int uint2v;

#define SS 8192
#define EE 512
#define NKB 16
#define AP 520    // A row pitch in shorts (1040 B)

__device__ __forceinline__ unsigned int f2bf1(float f) {
    unsigned int u = __builtin_bit_cast(unsigned int, f);
    return (u + 0x7fffu + ((u >> 16) & 1u)) >> 16;   // RNE, inputs finite
}
__device__ __forceinline__ unsigned int pack2(float lo, float hi) {
    return f2bf1(lo) | (f2bf1(hi) << 16);
}

#define WAITL()  asm volatile("s_waitcnt lgkmcnt(0)" ::: "memory")

// ---------- prep: W fp32 [512][512] -> bf16 ws [kb][n][32] (linear) ----------
__global__ void w_prep(const float* __restrict__ W, unsigned short* __restrict__ Wws) {
    int idx = blockIdx.x * 256 + threadIdx.x;        // 65536 threads x 4 elems
    int n  = idx >> 7;                               // W row (= output col) 0..511
    int kg = idx & 127;
    int k  = kg * 4;
    float4v v = *(const float4v*)(W + (size_t)n * EE + k);
    int kb = k >> 5, kl = k & 31;
    unsigned short* dst = Wws + ((size_t)kb * (EE * 32) + (size_t)n * 32 + kl);
    uint2v pk = { pack2(v.x, v.y), pack2(v.z, v.w) };
    *(uint2v*)dst = pk;
}

// ---------- main v6: quarter-streamed A, reg-streamed W, 4 barriers total ----------
// Block = (b, sc): 64x512 output panel. A_lds published in 4 quarters of 128 k-cols;
// quarter Q+1's x rows stream through 8 transient VGPRs during quarter Q's 4
// MFMA iterations (issue BEFORE b-prefetch -> consume waits are counted vmcnt(8),
// never a drain). W streams global->VGPR double-buffered, no barriers for W.
__global__ __launch_bounds__(256, 2)
void qmha_fused6(const float* __restrict__ x, const float* __restrict__ theta,
                 const unsigned short* __restrict__ Wws, float* __restrict__ out)
{
    __shared__ __attribute__((aligned(16))) unsigned short A_lds[64 * AP];  // 66560 B

    const int bx = blockIdx.x;                       // 1024 blocks
    const int b  = bx >> 7;
    const int sc = bx & 127;
    const int t = threadIdx.x, lane = t & 63, wid = t >> 6;
    const int fr = lane & 15, q = lane >> 4;

    // b-frag global base: wave wid owns W rows [wid*128, +128)
    const unsigned short* wbase = Wws + ((size_t)(wid * 128 + fr) * 32 + q * 8);

    // x-staging bases: wave wid stages rows  Q*16 + wid*4 + r  (r = 0..3)
    const float* xq = x + ((size_t)b * SS + (size_t)sc * 64 + (size_t)wid * 4) * EE + lane * 8;
    unsigned short* aw = A_lds + lane * AP + wid * 32;   // + Q*128 + r*8

    const float th0 = theta[0], th1 = theta[1], th2 = theta[2], th3 = theta[3];
    const float th4 = theta[4], th5 = theta[5], th6 = theta[6], th7 = theta[7];

    const int aoff = fr * AP + q * 8;                // + mt*16*AP + kb*32

    short8 bA[8], bB[8];
    float4v xv0, xv1, yv0, yv1;

#define BPF(KB, BUF) do { \
    const unsigned short* _wn = wbase + (size_t)(KB) * (EE * 32); \
    _Pragma("unroll") for (int _nt = 0; _nt < 8; ++_nt) \
        BUF[_nt] = *(const short8*)(_wn + _nt * 512); \
} while (0)

#define AMM(KB, BUF) do { \
    short8 _af[4]; \
    _Pragma("unroll") for (int _mt = 0; _mt < 4; ++_mt) \
        _af[_mt] = *(const short8*)&A_lds[aoff + _mt * 16 * AP + (KB) * 32]; \
    __builtin_amdgcn_s_setprio(1); \
    _Pragma("unroll") for (int _nt = 0; _nt < 8; ++_nt) \
        _Pragma("unroll") for (int _mt = 0; _mt < 4; ++_mt) \
            acc[_mt][_nt] = __builtin_amdgcn_mfma_f32_16x16x32_bf16(_af[_mt], BUF[_nt], acc[_mt][_nt], 0, 0, 0); \
    __builtin_amdgcn_s_setprio(0); \
} while (0)

#define XISSV(V0, V1, Q, R) do { \
    const float* _p = xq + (size_t)((Q) * 16 + (R)) * EE; \
    V0 = *(const float4v*)_p; V1 = *(const float4v*)(_p + 4); \
} while (0)

#define XCONV(V0, V1, Q, R) do { \
    float _c0 = __cosf((V0).x + th0), _c1 = __cosf((V0).y + th1); \
    float _c2 = __cosf((V0).z + th2), _c3 = __cosf((V0).w + th3); \
    float _c4 = __cosf((V1).x + th4), _c5 = __cosf((V1).y + th5); \
    float _c6 = __cosf((V1).z + th6), _c7 = __cosf((V1).w + th7); \
    uint4v _pk = { pack2(_c0,_c1), pack2(_c2,_c3), pack2(_c4,_c5), pack2(_c6,_c7) }; \
    *(uint4v*)(aw + (Q) * 128 + (R) * 8) = _pk; \
} while (0)

    // ---- prologue: b(kb0) in flight first, then stage quarter 0 (ping-pong) ----
    BPF(0, bA);
    XISSV(xv0, xv1, 0, 0); XISSV(yv0, yv1, 0, 1);
    XCONV(xv0, xv1, 0, 0); XISSV(xv0, xv1, 0, 2);
    XCONV(yv0, yv1, 0, 1); XISSV(yv0, yv1, 0, 3);
    XCONV(xv0, xv1, 0, 2); XCONV(yv0, yv1, 0, 3);
    WAITL();
    __builtin_amdgcn_s_barrier();    // publish quarter 0 (W loads stay in flight)

    float4v acc[4][8];
    #pragma unroll
    for (int i = 0; i < 4; ++i)
        #pragma unroll
        for (int j = 0; j < 8; ++j)
            acc[i][j] = (float4v){0.f, 0.f, 0.f, 0.f};

    // ---- Q=0 (kb 0..3), stream quarter 1 ----
    XISSV(xv0, xv1, 1, 0);                      BPF(1, bB); AMM(0, bA);
    XCONV(xv0, xv1, 1, 0); XISSV(xv0, xv1, 1, 1); BPF(2, bA); AMM(1, bB);
    XCONV(xv0, xv1, 1, 1); XISSV(xv0, xv1, 1, 2); BPF(3, bB); AMM(2, bA);
    XCONV(xv0, xv1, 1, 2); XISSV(xv0, xv1, 1, 3); BPF(4, bA); AMM(3, bB);
    XCONV(xv0, xv1, 1, 3);
    WAITL();
    __builtin_amdgcn_s_barrier();    // publish quarter 1

    // ---- Q=1 (kb 4..7), stream quarter 2 ----
    XISSV(xv0, xv1, 2, 0);                      BPF(5, bB); AMM(4, bA);
    XCONV(xv0, xv1, 2, 0); XISSV(xv0, xv1, 2, 1); BPF(6, bA); AMM(5, bB);
    XCONV(xv0, xv1, 2, 1); XISSV(xv0, xv1, 2, 2); BPF(7, bB); AMM(6, bA);
    XCONV(xv0, xv1, 2, 2); XISSV(xv0, xv1, 2, 3); BPF(8, bA); AMM(7, bB);
    XCONV(xv0, xv1, 2, 3);
    WAITL();
    __builtin_amdgcn_s_barrier();    // publish quarter 2

    // ---- Q=2 (kb 8..11), stream quarter 3 ----
    XISSV(xv0, xv1, 3, 0);                      BPF(9, bB);  AMM(8, bA);
    XCONV(xv0, xv1, 3, 0); XISSV(xv0, xv1, 3, 1); BPF(10, bA); AMM(9, bB);
    XCONV(xv0, xv1, 3, 1); XISSV(xv0, xv1, 3, 2); BPF(11, bB); AMM(10, bA);
    XCONV(xv0, xv1, 3, 2); XISSV(xv0, xv1, 3, 3); BPF(12, bA); AMM(11, bB);
    XCONV(xv0, xv1, 3, 3);
    WAITL();
    __builtin_amdgcn_s_barrier();    // publish quarter 3

    // ---- Q=3 (kb 12..15), no staging ----
    BPF(13, bB); AMM(12, bA);
    BPF(14, bA); AMM(13, bB);
    BPF(15, bB); AMM(14, bA);
                 AMM(15, bB);

    // ---- epilogue: C/D col=lane&15, row=(lane>>4)*4+reg (validated mapping) ----
    // out(m = mt*16 + q*4 + r, n = wid*128 + nt*16 + fr) at [b, m*128+sc, n]
    float* outb = out + (size_t)b * (SS * EE) + (size_t)sc * EE + wid * 128 + fr;
    #pragma unroll
    for (int mt = 0; mt < 4; ++mt) {
        #pragma unroll
        for (int r = 0; r < 4; ++r) {
            const int m = mt * 16 + q * 4 + r;
            float* po = outb + (size_t)m * (128 * EE);
            #pragma unroll
            for (int nt = 0; nt < 8; ++nt)
                po[nt * 16] = acc[mt][nt][r];
        }
    }
#undef BPF
#undef AMM
#undef XISSV
#undef XCONV
}

// ---------- fallback (round-1 kernel, used only if ws too small) ----------
#define AS 520
#define WSF 40
#define HH 64
__global__ __launch_bounds__(256, 2)
void qmha_fused_fb(const float* __restrict__ x, const float* __restrict__ theta,
                   const float* __restrict__ W, float* __restrict__ out)
{
    __shared__ __attribute__((aligned(16))) unsigned short A_lds[HH * AS];
    __shared__ __attribute__((aligned(16))) unsigned short W_lds[128 * WSF];
    const int bx = blockIdx.x;
    const int ntile = (bx >> 3) & 3;
    const int p = ((bx >> 5) << 3) | (bx & 7);
    const int b = p >> 7;
    const int sc = p & 127;
    const int t = threadIdx.x, lane = t & 63, wid = t >> 6;
    const int wn = t >> 1, wk = (t & 1) * 16;
    const float* Wbase = W + (size_t)(ntile * 128 + wn) * EE + wk;
    float4v wv0 = *(const float4v*)(Wbase + 0);
    float4v wv1 = *(const float4v*)(Wbase + 4);
    float4v wv2 = *(const float4v*)(Wbase + 8);
    float4v wv3 = *(const float4v*)(Wbase + 12);
    const float th0 = theta[0], th1 = theta[1], th2 = theta[2], th3 = theta[3];
    const float th4 = theta[4], th5 = theta[5], th6 = theta[6], th7 = theta[7];
    {
        const float* xb = x + ((size_t)b * SS + (size_t)sc * 64) * EE + lane * 8;
        #pragma unroll
        for (int it = 0; it < 16; ++it) {
            const int s_loc = wid * 16 + it;
            const float* px = xb + (size_t)s_loc * EE;
            float4v v0 = *(const float4v*)(px);
            float4v v1 = *(const float4v*)(px + 4);
            float c0 = __cosf(v0.x + th0), c1 = __cosf(v0.y + th1);
            float c2 = __cosf(v0.z + th2), c3 = __cosf(v0.w + th3);
            float c4 = __cosf(v1.x + th4), c5 = __cosf(v1.y + th5);
            float c6 = __cosf(v1.z + th6), c7 = __cosf(v1.w + th7);
            uint4v pk = { pack2(c0,c1), pack2(c2,c3), pack2(c4,c5), pack2(c6,c7) };
            *(uint4v*)&A_lds[lane * AS + s_loc * 8] = pk;
        }
    }
    float4v acc[2][4];
    #pragma unroll
    for (int i = 0; i < 2; ++i)
        #pragma unroll
        for (int j = 0; j < 4; ++j)
            acc[i][j] = (float4v){0.f, 0.f, 0.f, 0.f};
    const int m0 = (wid >> 1) * 32, n0l = (wid & 1) * 64;
    const int fr = lane & 15, q = lane >> 4;
    const unsigned short* Arow0 = &A_lds[(m0 + fr) * AS + q * 8];
    const unsigned short* Arow1 = Arow0 + 16 * AS;
    const unsigned short* Wrow  = &W_lds[(n0l + fr) * WSF + q * 8];
    for (int kb = 0; kb < NKB; ++kb) {
        __syncthreads();
        {
            uint4v lo = { pack2(wv0.x, wv0.y), pack2(wv0.z, wv0.w),
                          pack2(wv1.x, wv1.y), pack2(wv1.z, wv1.w) };
            uint4v hi = { pack2(wv2.x, wv2.y), pack2(wv2.z, wv2.w),
                          pack2(wv3.x, wv3.y), pack2(wv3.z, wv3.w) };
            *(uint4v*)&W_lds[wn * WSF + wk]     = lo;
            *(uint4v*)&W_lds[wn * WSF + wk + 8] = hi;
        }
        if (kb < NKB - 1) {
            const float* Wn = Wbase + (size_t)(kb + 1) * 32;
            wv0 = *(const float4v*)(Wn + 0);
            wv1 = *(const float4v*)(Wn + 4);
            wv2 = *(const float4v*)(Wn + 8);
            wv3 = *(const float4v*)(Wn + 12);
        }
        __syncthreads();
        short8 a0 = *(const short8*)(Arow0 + kb * 32);
        short8 a1 = *(const short8*)(Arow1 + kb * 32);
        short8 b0 = *(const short8*)(Wrow + 0 * 16 * WSF);
        short8 b1 = *(const short8*)(Wrow + 1 * 16 * WSF);
        short8 b2 = *(const short8*)(Wrow + 2 * 16 * WSF);
        short8 b3 = *(const short8*)(Wrow + 3 * 16 * WSF);
        acc[0][0] = __builtin_amdgcn_mfma_f32_16x16x32_bf16(a0, b0, acc[0][0], 0, 0, 0);
        acc[0][1] = __builtin_amdgcn_mfma_f32_16x16x32_bf16(a0, b1, acc[0][1], 0, 0, 0);
        acc[0][2] = __builtin_amdgcn_mfma_f32_16x16x32_bf16(a0, b2, acc[0][2], 0, 0, 0);
        acc[0][3] = __builtin_amdgcn_mfma_f32_16x16x32_bf16(a0, b3, acc[0][3], 0, 0, 0);
        acc[1][0] = __builtin_amdgcn_mfma_f32_16x16x32_bf16(a1, b0, acc[1][0], 0, 0, 0);
        acc[1][1] = __builtin_amdgcn_mfma_f32_16x16x32_bf16(a1, b1, acc[1][1], 0, 0, 0);
        acc[1][2] = __builtin_amdgcn_mfma_f32_16x16x32_bf16(a1, b2, acc[1][2], 0, 0, 0);
        acc[1][3] = __builtin_amdgcn_mfma_f32_16x16x32_bf16(a1, b3, acc[1][3], 0, 0, 0);
    }
    const int colbase = ntile * 128 + n0l + fr;
    #pragma unroll
    for (int mt = 0; mt < 2; ++mt) {
        #pragma unroll
        for (int r = 0; r < 4; ++r) {
            const int hrow = m0 + mt * 16 + q * 4 + r;
            float* po = out + ((size_t)b * SS + (size_t)hrow * 128 + sc) * EE + colbase;
            po[0 * 16] = acc[mt][0][r];
            po[1 * 16] = acc[mt][1][r];
            po[2 * 16] = acc[mt][2][r];
            po[3 * 16] = acc[mt][3][r];
        }
    }
}

extern "C" void kernel_launch(void* const* d_in, const int* in_sizes, int n_in,
                              void* d_out, int out_size, void* d_ws, size_t ws_size,
                              hipStream_t stream) {
    const float* x     = (const float*)d_in[0];
    const float* theta = (const float*)d_in[1];
    const float* W     = (const float*)d_in[2];
    float* out         = (float*)d_out;

    if (ws_size >= (size_t)EE * EE * sizeof(unsigned short)) {
        unsigned short* Wws = (unsigned short*)d_ws;
        w_prep<<<dim3(256), dim3(256), 0, stream>>>(W, Wws);
        qmha_fused6<<<dim3(1024), dim3(256), 0, stream>>>(x, theta, Wws, out);
    } else {
        qmha_fused_fb<<<dim3(4096), dim3(256), 0, stream>>>(x, theta, W, out);
    }
}